// Round 18
// baseline (146.905 us; speedup 1.0000x reference)
//
#include <hip/hip_runtime.h>
#include <hip/hip_fp16.h>
#include <math.h>

#define VV 5
#define CC 16
#define DD 32
#define HH 256
#define WW 320
#define HW (HH*WW)
#define ND 4            // depths per thread in k_var (one quad-interleaved group)
#define NXCD 8

// ---------------------------------------------------------------------------
// Kernel 1: projection setup (single thread). For each src view v=1..4:
// proj = mk_proj(p_v) @ inv(mk_proj(p_0)); store rot(3x3)+trans(3) in M[0..47].
// Also stores the (spatially-uniform) depth table dv[d] into M[64..95].
// ---------------------------------------------------------------------------
__global__ void k_setup(const float* __restrict__ projs,
                        const float* __restrict__ depth_vals,
                        float* __restrict__ M) {
    if (threadIdx.x != 0 || blockIdx.x != 0) return;

    float ref[16];
    {
        const float* E = projs + 0 * 32;
        const float* K = projs + 0 * 32 + 16;
        for (int i = 0; i < 16; i++) ref[i] = E[i];
        for (int i = 0; i < 3; i++)
            for (int j = 0; j < 4; j++) {
                float s = 0.f;
                for (int k = 0; k < 3; k++) s += K[i*4+k] * E[k*4+j];
                ref[i*4+j] = s;
            }
    }

    float a[16], inv[16];
    for (int i = 0; i < 16; i++) { a[i] = ref[i]; inv[i] = ((i % 5) == 0) ? 1.f : 0.f; }
    for (int col = 0; col < 4; col++) {
        int piv = col; float best = fabsf(a[col*4+col]);
        for (int r = col+1; r < 4; r++) {
            float v = fabsf(a[r*4+col]);
            if (v > best) { best = v; piv = r; }
        }
        if (piv != col) {
            for (int j = 0; j < 4; j++) {
                float t = a[col*4+j]; a[col*4+j] = a[piv*4+j]; a[piv*4+j] = t;
                t = inv[col*4+j]; inv[col*4+j] = inv[piv*4+j]; inv[piv*4+j] = t;
            }
        }
        float rd = 1.f / a[col*4+col];
        for (int j = 0; j < 4; j++) { a[col*4+j] *= rd; inv[col*4+j] *= rd; }
        for (int r = 0; r < 4; r++) {
            if (r == col) continue;
            float f = a[r*4+col];
            for (int j = 0; j < 4; j++) {
                a[r*4+j]   -= f * a[col*4+j];
                inv[r*4+j] -= f * inv[col*4+j];
            }
        }
    }

    for (int v = 1; v < VV; v++) {
        float s[16], p[16];
        const float* E = projs + v * 32;
        const float* K = projs + v * 32 + 16;
        for (int i = 0; i < 16; i++) s[i] = E[i];
        for (int i = 0; i < 3; i++)
            for (int j = 0; j < 4; j++) {
                float acc = 0.f;
                for (int k = 0; k < 3; k++) acc += K[i*4+k] * E[k*4+j];
                s[i*4+j] = acc;
            }
        for (int i = 0; i < 4; i++)
            for (int j = 0; j < 4; j++) {
                float acc = 0.f;
                for (int k = 0; k < 4; k++) acc += s[i*4+k] * inv[k*4+j];
                p[i*4+j] = acc;
            }
        float* o = M + (v - 1) * 12;
        o[0] = p[0];  o[1] = p[1];  o[2]  = p[2];
        o[3] = p[4];  o[4] = p[5];  o[5]  = p[6];
        o[6] = p[8];  o[7] = p[9];  o[8]  = p[10];
        o[9] = p[3];  o[10] = p[7]; o[11] = p[11];
    }

    // depth table: depth_values is a broadcast linspace -> uniform per d
    for (int d = 0; d < DD; d++) M[64 + d] = depth_vals[(size_t)d * HW];
}

// ---------------------------------------------------------------------------
// Kernel 1b: transpose features [V][C][H][W] -> [V][H*W][C] as fp16.
// ---------------------------------------------------------------------------
union H8 { float4 f4; __half2 h2[4]; };

__global__ __launch_bounds__(256) void k_transpose(const float* __restrict__ feat,
                                                   __half* __restrict__ tf) {
    const int idx = blockIdx.x * 256 + threadIdx.x;   // over V*HW
    if (idx >= VV * HW) return;
    const int v = idx / HW;
    const int pix = idx - v * HW;
    const float* src = feat + (size_t)v * CC * HW + pix;
    float t[CC];
    #pragma unroll
    for (int c = 0; c < CC; c++) t[c] = src[(size_t)c * HW];
    H8 o0, o1;
    #pragma unroll
    for (int g = 0; g < 4; g++) o0.h2[g] = __floats2half2_rn(t[2*g],     t[2*g+1]);
    #pragma unroll
    for (int g = 0; g < 4; g++) o1.h2[g] = __floats2half2_rn(t[8 + 2*g], t[8 + 2*g + 1]);
    float4* dst = (float4*)(tf + (size_t)idx * CC);
    dst[0] = o0.f4;
    dst[1] = o1.f4;
}

// ---------------------------------------------------------------------------
// gather8: accumulate one bilinear corner (16 channels, packed) into wv.
// Loads are independent across calls -> compiler clusters them for MLP.
// ---------------------------------------------------------------------------
__device__ __forceinline__ void gather8(const __half* __restrict__ tfv, int idx,
                                        __half2 wh, __half2* wv) {
    const float4* p4 = (const float4*)(tfv + (size_t)idx * CC);
    H8 u0, u1; u0.f4 = p4[0]; u1.f4 = p4[1];
    #pragma unroll
    for (int g = 0; g < 4; g++) {
        wv[g]     = __hfma2(wh, u0.h2[g], wv[g]);
        wv[4 + g] = __hfma2(wh, u1.h2[g], wv[4 + g]);
    }
}

// ---------------------------------------------------------------------------
// Kernel 2 (v11): variance volume, packed-f16 accumulation, native rcp,
// ND=4 depths QUAD-interleaved: all 4 projections up front, 16 corner
// gathers (32 independent float4 loads) in flight, 4 independent
// accumulation chains. Grid 2048, uniform depth from M-table, XCD swizzle.
// launch_bounds(320,2): 256-VGPR cap for the 4x accumulator state.
// ---------------------------------------------------------------------------
__global__ __launch_bounds__(320, 2) void k_var_t(const __half* __restrict__ tf,
                                                  const float* __restrict__ M,
                                                  __half* __restrict__ var) {
    // bijective chunked XCD swizzle: 2048 blocks = 8 chunks of 256
    const int orig = blockIdx.x;
    const int wg   = (orig & (NXCD - 1)) * 256 + (orig >> 3);
    const int chunk = wg >> 8;          // 0..7
    const int i     = wg & 255;
    const int y  = chunk * 32 + (i & 31);
    const int dg = i >> 5;              // 0..7

    const int x = threadIdx.x;
    const int pix = y * WW + x;

    // reference features (view 0), packed
    __half2 ref2[8];
    {
        const float4* r0 = (const float4*)(tf + (size_t)pix * CC);
        H8 a, b; a.f4 = r0[0]; b.f4 = r0[1];
        #pragma unroll
        for (int g = 0; g < 4; g++) { ref2[g] = a.h2[g]; ref2[4 + g] = b.h2[g]; }
    }

    // hoist depth-independent projection rows per view
    const float fx = (float)x, fy = (float)y;
    float ax[4], ay[4], az[4], bx[4], by[4], bz[4];
    #pragma unroll
    for (int v = 0; v < 4; v++) {
        const float* m = M + v * 12;
        ax[v] = m[0]*fx + m[1]*fy + m[2];
        ay[v] = m[3]*fx + m[4]*fy + m[5];
        az[v] = m[6]*fx + m[7]*fy + m[8];
        bx[v] = m[9]; by[v] = m[10]; bz[v] = m[11];
    }

    const float invV = 1.f / (float)VV;

    // per-view projection -> corner indices + packed weights (suffix S)
    #define MKGATH(S, DEPTH) \
        int i00##S, i01##S, i10##S, i11##S; \
        __half2 w00##S, w01##S, w10##S, w11##S; \
        { \
            const float pz = az[v] * (DEPTH) + bz[v]; \
            const float rz = __builtin_amdgcn_rcpf(pz); \
            const float px = (ax[v] * (DEPTH) + bx[v]) * rz; \
            const float py = (ay[v] * (DEPTH) + by[v]) * rz; \
            const float x0f = floorf(px), y0f = floorf(py); \
            const float wx = px - x0f,    wy = py - y0f; \
            const int x0 = (int)x0f, y0i = (int)y0f; \
            const int x1 = x0 + 1,   y1 = y0i + 1; \
            const float mx0 = (x0 >= 0 && x0 < WW) ? 1.f : 0.f; \
            const float mx1 = (x1 >= 0 && x1 < WW) ? 1.f : 0.f; \
            const float my0 = (y0i >= 0 && y0i < HH) ? 1.f : 0.f; \
            const float my1 = (y1 >= 0 && y1 < HH) ? 1.f : 0.f; \
            const int cx0 = min(max(x0, 0), WW - 1), cx1 = min(max(x1, 0), WW - 1); \
            const int cy0 = min(max(y0i, 0), HH - 1), cy1 = min(max(y1, 0), HH - 1); \
            w00##S = __float2half2_rn((1.f - wx) * (1.f - wy) * mx0 * my0); \
            w01##S = __float2half2_rn(wx * (1.f - wy)         * mx1 * my0); \
            w10##S = __float2half2_rn((1.f - wx) * wy         * mx0 * my1); \
            w11##S = __float2half2_rn(wx * wy                 * mx1 * my1); \
            i00##S = cy0 * WW + cx0; i01##S = cy0 * WW + cx1; \
            i10##S = cy1 * WW + cx0; i11##S = cy1 * WW + cx1; \
        }

    const int d0 = dg * ND;
    const float depthA = M[64 + d0 + 0];    // uniform -> SGPR
    const float depthB = M[64 + d0 + 1];
    const float depthC = M[64 + d0 + 2];
    const float depthD = M[64 + d0 + 3];

    __half2 sumA[8], sqA[8], sumB[8], sqB[8], sumC[8], sqC[8], sumD[8], sqD[8];
    #pragma unroll
    for (int g = 0; g < 8; g++) {
        const __half2 r = ref2[g];
        const __half2 rr = __hmul2(r, r);
        sumA[g] = r;  sqA[g] = rr;
        sumB[g] = r;  sqB[g] = rr;
        sumC[g] = r;  sqC[g] = rr;
        sumD[g] = r;  sqD[g] = rr;
    }

    #pragma unroll
    for (int v = 0; v < 4; v++) {
        MKGATH(A, depthA)
        MKGATH(B, depthB)
        MKGATH(C, depthC)
        MKGATH(D, depthD)

        const __half* tfv = tf + (size_t)(v + 1) * HW * CC;
        __half2 wvA[8], wvB[8], wvC[8], wvD[8];
        #pragma unroll
        for (int g = 0; g < 8; g++) {
            wvA[g] = __float2half2_rn(0.f);
            wvB[g] = __float2half2_rn(0.f);
            wvC[g] = __float2half2_rn(0.f);
            wvD[g] = __float2half2_rn(0.f);
        }

        // interleave all 4 depths' corner gathers -> 32 loads in flight
        gather8(tfv, i00A, w00A, wvA);  gather8(tfv, i00B, w00B, wvB);
        gather8(tfv, i00C, w00C, wvC);  gather8(tfv, i00D, w00D, wvD);
        gather8(tfv, i01A, w01A, wvA);  gather8(tfv, i01B, w01B, wvB);
        gather8(tfv, i01C, w01C, wvC);  gather8(tfv, i01D, w01D, wvD);
        gather8(tfv, i10A, w10A, wvA);  gather8(tfv, i10B, w10B, wvB);
        gather8(tfv, i10C, w10C, wvC);  gather8(tfv, i10D, w10D, wvD);
        gather8(tfv, i11A, w11A, wvA);  gather8(tfv, i11B, w11B, wvB);
        gather8(tfv, i11C, w11C, wvC);  gather8(tfv, i11D, w11D, wvD);

        #pragma unroll
        for (int g = 0; g < 8; g++) {
            sumA[g] = __hadd2(sumA[g], wvA[g]);
            sqA[g]  = __hfma2(wvA[g], wvA[g], sqA[g]);
            sumB[g] = __hadd2(sumB[g], wvB[g]);
            sqB[g]  = __hfma2(wvB[g], wvB[g], sqB[g]);
            sumC[g] = __hadd2(sumC[g], wvC[g]);
            sqC[g]  = __hfma2(wvC[g], wvC[g], sqC[g]);
            sumD[g] = __hadd2(sumD[g], wvD[g]);
            sqD[g]  = __hfma2(wvD[g], wvD[g], sqD[g]);
        }
    }

    #define WRITEOUT(S, DI) \
        _Pragma("unroll") \
        for (int g = 0; g < 8; g++) { \
            const float s0 = __low2float(sum##S[g]), s1 = __high2float(sum##S[g]); \
            const float q0 = __low2float(sq##S[g]),  q1 = __high2float(sq##S[g]); \
            const float m0 = s0 * invV, m1 = s1 * invV; \
            var[(size_t)(2*g)     * DD * HW + (size_t)(DI) * HW + pix] = __float2half(q0 * invV - m0 * m0); \
            var[(size_t)(2*g + 1) * DD * HW + (size_t)(DI) * HW + pix] = __float2half(q1 * invV - m1 * m1); \
        }

    WRITEOUT(A, d0 + 0)
    WRITEOUT(B, d0 + 1)
    WRITEOUT(C, d0 + 2)
    WRITEOUT(D, d0 + 3)
    #undef WRITEOUT
    #undef MKGATH
}

// ---------------------------------------------------------------------------
// Kernel 3 (v8, round-14 proven): per-slice 2D conv, 4-row tiles, grid 2048.
// u[kd][dd][pix] = sum_c conv2d(var[c][dd], w[c][kd]); d-merge in k_softmax.
// ---------------------------------------------------------------------------
#define SROW (WW + 2)
__global__ __launch_bounds__(320) void k_conv2d(const __half* __restrict__ var,
                                                const float* __restrict__ w,
                                                __half* __restrict__ u) {
    // XCD-chunked swizzle: 2048 blocks = 8 chunks of 256; ytile fast
    const int orig = blockIdx.x;
    const int wg   = (orig & (NXCD - 1)) * 256 + (orig >> 3);
    const int dd    = wg >> 6;           // 0..31
    const int ytile = wg & 63;           // 0..63 (4 output rows each)

    __shared__ float s[2][6][SROW];

    const int tid = threadIdx.x;
    const int p   = tid % 160;           // x-pair index
    const int ry  = tid / 160;           // 0 or 1
    const int lr  = ry * 2;              // local row base for compute window

    // zero halo columns (cols 0 and WW+1) once: 2 bufs x 6 rows x 2 sides
    if (tid < 24) {
        const int b = tid / 12, rem = tid % 12, r = rem >> 1, side = rem & 1;
        s[b][r][side * (WW + 1)] = 0.f;
    }

    // staging addressing: 960 half2 per tile; thread covers k=0..2,
    // idx = tid + 320k -> row r = idx/160 (0..5), pair px = idx%160.
    const __half2* vbase = (const __half2*)(var + (size_t)dd * HW);
    int srow[3], spx[3];
    bool svok[3];
    #pragma unroll
    for (int k = 0; k < 3; k++) {
        const int idx = tid + k * 320;
        const int r = idx / 160;
        spx[k] = idx - r * 160;
        srow[k] = r;
        const int yy = ytile * 4 - 1 + r;
        svok[k] = (yy >= 0 && yy < HH);
        // precompute clamped global row offset in half2 units
        spx[k] += min(max(yy, 0), HH - 1) * 160;
    }

    __half2 stg[3];
    #define LOADREG(c) { \
        const __half2* cb = vbase + (size_t)(c) * DD * HW / 2; \
        _Pragma("unroll") \
        for (int k = 0; k < 3; k++) stg[k] = cb[spx[k]]; }

    #define WRITELDS(b) { \
        _Pragma("unroll") \
        for (int k = 0; k < 3; k++) { \
            const int r = srow[k]; \
            const int col = 1 + 2 * (spx[k] - (spx[k] / 160) * 160); \
            const float zz = svok[k] ? 1.f : 0.f; \
            s[b][r][col]     = zz * __low2float(stg[k]); \
            s[b][r][col + 1] = zz * __high2float(stg[k]); } }

    float acc[2][3][2];                  // [dy][kd][x01]
    #pragma unroll
    for (int dy = 0; dy < 2; dy++)
        #pragma unroll
        for (int kd = 0; kd < 3; kd++) { acc[dy][kd][0] = 0.f; acc[dy][kd][1] = 0.f; }

    LOADREG(0)
    WRITELDS(0)

    for (int c = 0; c < CC; c++) {
        const int b = c & 1;
        __syncthreads();                 // buf b staged, prev reads done

        if (c + 1 < CC) LOADREG(c + 1)   // issue next tile's global loads

        float wr[27];
        #pragma unroll
        for (int j = 0; j < 27; j++) wr[j] = w[c * 27 + j];   // uniform -> SGPR

        // read 4 window rows from LDS: cols 2p..2p+3 (two b64 reads per row)
        float A1[4], B0[4], B1[4], C0[4];
        #pragma unroll
        for (int r = 0; r < 4; r++) {
            const float2 ab = *(const float2*)&s[b][lr + r][2 * p];
            const float2 cd = *(const float2*)&s[b][lr + r][2 * p + 2];
            A1[r] = ab.x; B0[r] = ab.y; B1[r] = cd.x; C0[r] = cd.y;
        }

        #pragma unroll
        for (int kd = 0; kd < 3; kd++) {
            const float* k9 = wr + kd * 9;
            #pragma unroll
            for (int dy = 0; dy < 2; dy++) {
                float a0 = 0.f, a1 = 0.f;
                #pragma unroll
                for (int ky = 0; ky < 3; ky++) {
                    const int r = dy + ky;
                    a0 += k9[ky*3+0]*A1[r] + k9[ky*3+1]*B0[r] + k9[ky*3+2]*B1[r];
                    a1 += k9[ky*3+0]*B0[r] + k9[ky*3+1]*B1[r] + k9[ky*3+2]*C0[r];
                }
                acc[dy][kd][0] += a0;
                acc[dy][kd][1] += a1;
            }
        }

        if (c + 1 < CC) WRITELDS(b ^ 1)  // waits vmcnt after FMAs
    }

    const int y0t = ytile * 4 + ry * 2;
    #pragma unroll
    for (int kd = 0; kd < 3; kd++) {
        #pragma unroll
        for (int dy = 0; dy < 2; dy++) {
            __half2* co = (__half2*)(u + ((size_t)kd * DD + dd) * HW + (size_t)(y0t + dy) * WW);
            co[p] = __floats2half2_rn(acc[dy][kd][0], acc[dy][kd][1]);
        }
    }
}

// ---------------------------------------------------------------------------
// Kernel 4 (v1, round-14 proven): d-merge of fp16 u (3-point) + softmax over
// D + depth + conf. One pixel per thread; u loaded via half2 + parity select.
// out layout: [0,HW) depth | [HW,2HW) conf | [2HW, 2HW+D*HW) prob
// ---------------------------------------------------------------------------
__global__ __launch_bounds__(256) void k_softmax(const __half* __restrict__ u,
                                                 const float* __restrict__ M,
                                                 float* __restrict__ out) {
    const int idx = blockIdx.x * blockDim.x + threadIdx.x;
    if (idx >= HW) return;

    const __half2* uh = (const __half2*)u;
    const int h  = idx >> 1;
    const bool hi = (idx & 1) != 0;
    const size_t S = (size_t)DD * (HW / 2);

    float c[DD];
    float m = -INFINITY;
    #pragma unroll
    for (int d = 0; d < DD; d++) {
        __half2 a = uh[S + (size_t)d * (HW / 2) + h];                 // u1[d]
        float v = hi ? __high2float(a) : __low2float(a);
        if (d > 0) {
            __half2 b = uh[(size_t)(d - 1) * (HW / 2) + h];           // u0[d-1]
            v += hi ? __high2float(b) : __low2float(b);
        }
        if (d < DD - 1) {
            __half2 e = uh[2 * S + (size_t)(d + 1) * (HW / 2) + h];   // u2[d+1]
            v += hi ? __high2float(e) : __low2float(e);
        }
        c[d] = v;
        m = fmaxf(m, v);
    }
    float s = 0.f;
    #pragma unroll
    for (int d = 0; d < DD; d++) {
        c[d] = expf(c[d] - m);
        s += c[d];
    }
    const float inv = 1.f / s;

    float depth = 0.f, di_f = 0.f;
    #pragma unroll
    for (int d = 0; d < DD; d++) {
        float p = c[d] * inv;
        c[d] = p;
        out[2 * HW + (size_t)d * HW + idx] = p;
        depth += p * M[64 + d];       // uniform depth table
        di_f  += p * (float)d;
    }
    out[idx] = depth;

    int di = (int)di_f;
    di = min(max(di, 0), DD - 1);
    float cur = 0.f, nxt = 0.f;
    #pragma unroll
    for (int d = 0; d < DD; d++) {
        if (d == di)     cur = c[d];
        if (d == di + 1) nxt = c[d];
    }
    out[HW + idx] = cur + nxt;   // nxt stays 0 when di == DD-1
}

// ---------------------------------------------------------------------------
extern "C" void kernel_launch(void* const* d_in, const int* in_sizes, int n_in,
                              void* d_out, int out_size, void* d_ws, size_t ws_size,
                              hipStream_t stream) {
    const float* features = (const float*)d_in[0];
    const float* projs    = (const float*)d_in[1];
    const float* depthv   = (const float*)d_in[2];
    const float* regw     = (const float*)d_in[3];
    float* out = (float*)d_out;

    const size_t tf_elems  = (size_t)VV * HW * CC;       // 6.55M halves (13.1 MB)
    const size_t var_elems = (size_t)CC * DD * HW;       // 41.9M halves (83.9 MB)

    float*  M    = (float*)d_ws;                         // 96 floats used
    __half* tf   = (__half*)((char*)d_ws + 4096);
    __half* var  = tf + tf_elems;
    __half* u    = var + var_elems;                      // 3*DD*HW halves (15.7 MB)

    k_setup<<<1, 64, 0, stream>>>(projs, depthv, M);
    k_transpose<<<(VV * HW + 255) / 256, 256, 0, stream>>>(features, tf);

    k_var_t<<<HH * (DD / ND), WW, 0, stream>>>(tf, M, var);

    k_conv2d<<<64 * 32, WW, 0, stream>>>(var, regw, u);

    k_softmax<<<(HW + 255) / 256, 256, 0, stream>>>(u, M, out);
}

// Round 19
// 126.204 us; speedup vs baseline: 1.1640x; 1.1640x over previous
//
#include <hip/hip_runtime.h>
#include <hip/hip_fp16.h>
#include <math.h>

#define VV 5
#define CC 16
#define DD 32
#define HH 256
#define WW 320
#define HW (HH*WW)
#define ND 4            // depths per thread in k_var (2 dual-depth pairs) — measured optimum
#define NXCD 8

// ---------------------------------------------------------------------------
// Kernel 1: projection setup (single thread). For each src view v=1..4:
// proj = mk_proj(p_v) @ inv(mk_proj(p_0)); store rot(3x3)+trans(3) in M[0..47].
// Also stores the (spatially-uniform) depth table dv[d] into M[64..95].
// ---------------------------------------------------------------------------
__global__ void k_setup(const float* __restrict__ projs,
                        const float* __restrict__ depth_vals,
                        float* __restrict__ M) {
    if (threadIdx.x != 0 || blockIdx.x != 0) return;

    float ref[16];
    {
        const float* E = projs + 0 * 32;
        const float* K = projs + 0 * 32 + 16;
        for (int i = 0; i < 16; i++) ref[i] = E[i];
        for (int i = 0; i < 3; i++)
            for (int j = 0; j < 4; j++) {
                float s = 0.f;
                for (int k = 0; k < 3; k++) s += K[i*4+k] * E[k*4+j];
                ref[i*4+j] = s;
            }
    }

    float a[16], inv[16];
    for (int i = 0; i < 16; i++) { a[i] = ref[i]; inv[i] = ((i % 5) == 0) ? 1.f : 0.f; }
    for (int col = 0; col < 4; col++) {
        int piv = col; float best = fabsf(a[col*4+col]);
        for (int r = col+1; r < 4; r++) {
            float v = fabsf(a[r*4+col]);
            if (v > best) { best = v; piv = r; }
        }
        if (piv != col) {
            for (int j = 0; j < 4; j++) {
                float t = a[col*4+j]; a[col*4+j] = a[piv*4+j]; a[piv*4+j] = t;
                t = inv[col*4+j]; inv[col*4+j] = inv[piv*4+j]; inv[piv*4+j] = t;
            }
        }
        float rd = 1.f / a[col*4+col];
        for (int j = 0; j < 4; j++) { a[col*4+j] *= rd; inv[col*4+j] *= rd; }
        for (int r = 0; r < 4; r++) {
            if (r == col) continue;
            float f = a[r*4+col];
            for (int j = 0; j < 4; j++) {
                a[r*4+j]   -= f * a[col*4+j];
                inv[r*4+j] -= f * inv[col*4+j];
            }
        }
    }

    for (int v = 1; v < VV; v++) {
        float s[16], p[16];
        const float* E = projs + v * 32;
        const float* K = projs + v * 32 + 16;
        for (int i = 0; i < 16; i++) s[i] = E[i];
        for (int i = 0; i < 3; i++)
            for (int j = 0; j < 4; j++) {
                float acc = 0.f;
                for (int k = 0; k < 3; k++) acc += K[i*4+k] * E[k*4+j];
                s[i*4+j] = acc;
            }
        for (int i = 0; i < 4; i++)
            for (int j = 0; j < 4; j++) {
                float acc = 0.f;
                for (int k = 0; k < 4; k++) acc += s[i*4+k] * inv[k*4+j];
                p[i*4+j] = acc;
            }
        float* o = M + (v - 1) * 12;
        o[0] = p[0];  o[1] = p[1];  o[2]  = p[2];
        o[3] = p[4];  o[4] = p[5];  o[5]  = p[6];
        o[6] = p[8];  o[7] = p[9];  o[8]  = p[10];
        o[9] = p[3];  o[10] = p[7]; o[11] = p[11];
    }

    // depth table: depth_values is a broadcast linspace -> uniform per d
    for (int d = 0; d < DD; d++) M[64 + d] = depth_vals[(size_t)d * HW];
}

// ---------------------------------------------------------------------------
// Kernel 1b: transpose features [V][C][H][W] -> [V][H*W][C] as fp16.
// ---------------------------------------------------------------------------
union H8 { float4 f4; __half2 h2[4]; };

__global__ __launch_bounds__(256) void k_transpose(const float* __restrict__ feat,
                                                   __half* __restrict__ tf) {
    const int idx = blockIdx.x * 256 + threadIdx.x;   // over V*HW
    if (idx >= VV * HW) return;
    const int v = idx / HW;
    const int pix = idx - v * HW;
    const float* src = feat + (size_t)v * CC * HW + pix;
    float t[CC];
    #pragma unroll
    for (int c = 0; c < CC; c++) t[c] = src[(size_t)c * HW];
    H8 o0, o1;
    #pragma unroll
    for (int g = 0; g < 4; g++) o0.h2[g] = __floats2half2_rn(t[2*g],     t[2*g+1]);
    #pragma unroll
    for (int g = 0; g < 4; g++) o1.h2[g] = __floats2half2_rn(t[8 + 2*g], t[8 + 2*g + 1]);
    float4* dst = (float4*)(tf + (size_t)idx * CC);
    dst[0] = o0.f4;
    dst[1] = o1.f4;
}

// ---------------------------------------------------------------------------
// gather8: accumulate one bilinear corner (16 channels, packed) into wv.
// Loads are independent across calls -> compiler clusters them for MLP.
// ---------------------------------------------------------------------------
__device__ __forceinline__ void gather8(const __half* __restrict__ tfv, int idx,
                                        __half2 wh, __half2* wv) {
    const float4* p4 = (const float4*)(tfv + (size_t)idx * CC);
    H8 u0, u1; u0.f4 = p4[0]; u1.f4 = p4[1];
    #pragma unroll
    for (int g = 0; g < 4; g++) {
        wv[g]     = __hfma2(wh, u0.h2[g], wv[g]);
        wv[4 + g] = __hfma2(wh, u1.h2[g], wv[4 + g]);
    }
}

// ---------------------------------------------------------------------------
// Kernel 2 (v10, round-13/14/17 proven): variance volume, packed-f16
// accumulation, native rcp, ND=4 depths as 2 interleaved dual-depth pairs
// (2x MLP), grid 2048, uniform depth from M-table, XCD-chunked swizzle.
// ---------------------------------------------------------------------------
__global__ __launch_bounds__(320, 4) void k_var_t(const __half* __restrict__ tf,
                                                  const float* __restrict__ M,
                                                  __half* __restrict__ var) {
    // bijective chunked XCD swizzle: 2048 blocks = 8 chunks of 256
    const int orig = blockIdx.x;
    const int wg   = (orig & (NXCD - 1)) * 256 + (orig >> 3);
    const int chunk = wg >> 8;          // 0..7
    const int i     = wg & 255;
    const int y  = chunk * 32 + (i & 31);
    const int dg = i >> 5;              // 0..7

    const int x = threadIdx.x;
    const int pix = y * WW + x;

    // reference features (view 0), packed
    __half2 ref2[8];
    {
        const float4* r0 = (const float4*)(tf + (size_t)pix * CC);
        H8 a, b; a.f4 = r0[0]; b.f4 = r0[1];
        #pragma unroll
        for (int g = 0; g < 4; g++) { ref2[g] = a.h2[g]; ref2[4 + g] = b.h2[g]; }
    }

    // hoist depth-independent projection rows per view
    const float fx = (float)x, fy = (float)y;
    float ax[4], ay[4], az[4], bx[4], by[4], bz[4];
    #pragma unroll
    for (int v = 0; v < 4; v++) {
        const float* m = M + v * 12;
        ax[v] = m[0]*fx + m[1]*fy + m[2];
        ay[v] = m[3]*fx + m[4]*fy + m[5];
        az[v] = m[6]*fx + m[7]*fy + m[8];
        bx[v] = m[9]; by[v] = m[10]; bz[v] = m[11];
    }

    const float invV = 1.f / (float)VV;

    // per-view projection -> corner indices + packed weights (suffix S)
    #define MKGATH(S, DEPTH) \
        int i00##S, i01##S, i10##S, i11##S; \
        __half2 w00##S, w01##S, w10##S, w11##S; \
        { \
            const float pz = az[v] * (DEPTH) + bz[v]; \
            const float rz = __builtin_amdgcn_rcpf(pz); \
            const float px = (ax[v] * (DEPTH) + bx[v]) * rz; \
            const float py = (ay[v] * (DEPTH) + by[v]) * rz; \
            const float x0f = floorf(px), y0f = floorf(py); \
            const float wx = px - x0f,    wy = py - y0f; \
            const int x0 = (int)x0f, y0i = (int)y0f; \
            const int x1 = x0 + 1,   y1 = y0i + 1; \
            const float mx0 = (x0 >= 0 && x0 < WW) ? 1.f : 0.f; \
            const float mx1 = (x1 >= 0 && x1 < WW) ? 1.f : 0.f; \
            const float my0 = (y0i >= 0 && y0i < HH) ? 1.f : 0.f; \
            const float my1 = (y1 >= 0 && y1 < HH) ? 1.f : 0.f; \
            const int cx0 = min(max(x0, 0), WW - 1), cx1 = min(max(x1, 0), WW - 1); \
            const int cy0 = min(max(y0i, 0), HH - 1), cy1 = min(max(y1, 0), HH - 1); \
            w00##S = __float2half2_rn((1.f - wx) * (1.f - wy) * mx0 * my0); \
            w01##S = __float2half2_rn(wx * (1.f - wy)         * mx1 * my0); \
            w10##S = __float2half2_rn((1.f - wx) * wy         * mx0 * my1); \
            w11##S = __float2half2_rn(wx * wy                 * mx1 * my1); \
            i00##S = cy0 * WW + cx0; i01##S = cy0 * WW + cx1; \
            i10##S = cy1 * WW + cx0; i11##S = cy1 * WW + cx1; \
        }

    #pragma unroll
    for (int dp = 0; dp < ND / 2; dp++) {
        const int dA = dg * ND + 2 * dp;
        const int dB = dA + 1;
        const float depthA = M[64 + dA];        // uniform -> SGPR
        const float depthB = M[64 + dB];

        __half2 sumA[8], sqA[8], sumB[8], sqB[8];
        #pragma unroll
        for (int g = 0; g < 8; g++) {
            sumA[g] = ref2[g];  sqA[g] = __hmul2(ref2[g], ref2[g]);
            sumB[g] = ref2[g];  sqB[g] = __hmul2(ref2[g], ref2[g]);
        }

        #pragma unroll
        for (int v = 0; v < 4; v++) {
            MKGATH(A, depthA)
            MKGATH(B, depthB)

            const __half* tfv = tf + (size_t)(v + 1) * HW * CC;
            __half2 wvA[8], wvB[8];
            #pragma unroll
            for (int g = 0; g < 8; g++) {
                wvA[g] = __float2half2_rn(0.f);
                wvB[g] = __float2half2_rn(0.f);
            }

            // interleave both depths' corner gathers -> 16 loads in flight
            gather8(tfv, i00A, w00A, wvA);  gather8(tfv, i00B, w00B, wvB);
            gather8(tfv, i01A, w01A, wvA);  gather8(tfv, i01B, w01B, wvB);
            gather8(tfv, i10A, w10A, wvA);  gather8(tfv, i10B, w10B, wvB);
            gather8(tfv, i11A, w11A, wvA);  gather8(tfv, i11B, w11B, wvB);

            #pragma unroll
            for (int g = 0; g < 8; g++) {
                sumA[g] = __hadd2(sumA[g], wvA[g]);
                sqA[g]  = __hfma2(wvA[g], wvA[g], sqA[g]);
                sumB[g] = __hadd2(sumB[g], wvB[g]);
                sqB[g]  = __hfma2(wvB[g], wvB[g], sqB[g]);
            }
        }

        #pragma unroll
        for (int g = 0; g < 8; g++) {
            {
                const float s0 = __low2float(sumA[g]), s1 = __high2float(sumA[g]);
                const float q0 = __low2float(sqA[g]),  q1 = __high2float(sqA[g]);
                const float m0 = s0 * invV, m1 = s1 * invV;
                var[(size_t)(2*g)     * DD * HW + (size_t)dA * HW + pix] = __float2half(q0 * invV - m0 * m0);
                var[(size_t)(2*g + 1) * DD * HW + (size_t)dA * HW + pix] = __float2half(q1 * invV - m1 * m1);
            }
            {
                const float s0 = __low2float(sumB[g]), s1 = __high2float(sumB[g]);
                const float q0 = __low2float(sqB[g]),  q1 = __high2float(sqB[g]);
                const float m0 = s0 * invV, m1 = s1 * invV;
                var[(size_t)(2*g)     * DD * HW + (size_t)dB * HW + pix] = __float2half(q0 * invV - m0 * m0);
                var[(size_t)(2*g + 1) * DD * HW + (size_t)dB * HW + pix] = __float2half(q1 * invV - m1 * m1);
            }
        }
    }
    #undef MKGATH
}

// ---------------------------------------------------------------------------
// Kernel 3 (v8, round-14 proven): per-slice 2D conv, 4-row tiles, grid 2048.
// u[kd][dd][pix] = sum_c conv2d(var[c][dd], w[c][kd]); d-merge in k_softmax.
// ---------------------------------------------------------------------------
#define SROW (WW + 2)
__global__ __launch_bounds__(320) void k_conv2d(const __half* __restrict__ var,
                                                const float* __restrict__ w,
                                                __half* __restrict__ u) {
    // XCD-chunked swizzle: 2048 blocks = 8 chunks of 256; ytile fast
    const int orig = blockIdx.x;
    const int wg   = (orig & (NXCD - 1)) * 256 + (orig >> 3);
    const int dd    = wg >> 6;           // 0..31
    const int ytile = wg & 63;           // 0..63 (4 output rows each)

    __shared__ float s[2][6][SROW];

    const int tid = threadIdx.x;
    const int p   = tid % 160;           // x-pair index
    const int ry  = tid / 160;           // 0 or 1
    const int lr  = ry * 2;              // local row base for compute window

    // zero halo columns (cols 0 and WW+1) once: 2 bufs x 6 rows x 2 sides
    if (tid < 24) {
        const int b = tid / 12, rem = tid % 12, r = rem >> 1, side = rem & 1;
        s[b][r][side * (WW + 1)] = 0.f;
    }

    // staging addressing: 960 half2 per tile; thread covers k=0..2,
    // idx = tid + 320k -> row r = idx/160 (0..5), pair px = idx%160.
    const __half2* vbase = (const __half2*)(var + (size_t)dd * HW);
    int srow[3], spx[3];
    bool svok[3];
    #pragma unroll
    for (int k = 0; k < 3; k++) {
        const int idx = tid + k * 320;
        const int r = idx / 160;
        spx[k] = idx - r * 160;
        srow[k] = r;
        const int yy = ytile * 4 - 1 + r;
        svok[k] = (yy >= 0 && yy < HH);
        // precompute clamped global row offset in half2 units
        spx[k] += min(max(yy, 0), HH - 1) * 160;
    }

    __half2 stg[3];
    #define LOADREG(c) { \
        const __half2* cb = vbase + (size_t)(c) * DD * HW / 2; \
        _Pragma("unroll") \
        for (int k = 0; k < 3; k++) stg[k] = cb[spx[k]]; }

    #define WRITELDS(b) { \
        _Pragma("unroll") \
        for (int k = 0; k < 3; k++) { \
            const int r = srow[k]; \
            const int col = 1 + 2 * (spx[k] - (spx[k] / 160) * 160); \
            const float zz = svok[k] ? 1.f : 0.f; \
            s[b][r][col]     = zz * __low2float(stg[k]); \
            s[b][r][col + 1] = zz * __high2float(stg[k]); } }

    float acc[2][3][2];                  // [dy][kd][x01]
    #pragma unroll
    for (int dy = 0; dy < 2; dy++)
        #pragma unroll
        for (int kd = 0; kd < 3; kd++) { acc[dy][kd][0] = 0.f; acc[dy][kd][1] = 0.f; }

    LOADREG(0)
    WRITELDS(0)

    for (int c = 0; c < CC; c++) {
        const int b = c & 1;
        __syncthreads();                 // buf b staged, prev reads done

        if (c + 1 < CC) LOADREG(c + 1)   // issue next tile's global loads

        float wr[27];
        #pragma unroll
        for (int j = 0; j < 27; j++) wr[j] = w[c * 27 + j];   // uniform -> SGPR

        // read 4 window rows from LDS: cols 2p..2p+3 (two b64 reads per row)
        float A1[4], B0[4], B1[4], C0[4];
        #pragma unroll
        for (int r = 0; r < 4; r++) {
            const float2 ab = *(const float2*)&s[b][lr + r][2 * p];
            const float2 cd = *(const float2*)&s[b][lr + r][2 * p + 2];
            A1[r] = ab.x; B0[r] = ab.y; B1[r] = cd.x; C0[r] = cd.y;
        }

        #pragma unroll
        for (int kd = 0; kd < 3; kd++) {
            const float* k9 = wr + kd * 9;
            #pragma unroll
            for (int dy = 0; dy < 2; dy++) {
                float a0 = 0.f, a1 = 0.f;
                #pragma unroll
                for (int ky = 0; ky < 3; ky++) {
                    const int r = dy + ky;
                    a0 += k9[ky*3+0]*A1[r] + k9[ky*3+1]*B0[r] + k9[ky*3+2]*B1[r];
                    a1 += k9[ky*3+0]*B0[r] + k9[ky*3+1]*B1[r] + k9[ky*3+2]*C0[r];
                }
                acc[dy][kd][0] += a0;
                acc[dy][kd][1] += a1;
            }
        }

        if (c + 1 < CC) WRITELDS(b ^ 1)  // waits vmcnt after FMAs
    }

    const int y0t = ytile * 4 + ry * 2;
    #pragma unroll
    for (int kd = 0; kd < 3; kd++) {
        #pragma unroll
        for (int dy = 0; dy < 2; dy++) {
            __half2* co = (__half2*)(u + ((size_t)kd * DD + dd) * HW + (size_t)(y0t + dy) * WW);
            co[p] = __floats2half2_rn(acc[dy][kd][0], acc[dy][kd][1]);
        }
    }
}

// ---------------------------------------------------------------------------
// Kernel 4 (v1, round-14 proven): d-merge of fp16 u (3-point) + softmax over
// D + depth + conf. One pixel per thread; u loaded via half2 + parity select.
// out layout: [0,HW) depth | [HW,2HW) conf | [2HW, 2HW+D*HW) prob
// ---------------------------------------------------------------------------
__global__ __launch_bounds__(256) void k_softmax(const __half* __restrict__ u,
                                                 const float* __restrict__ M,
                                                 float* __restrict__ out) {
    const int idx = blockIdx.x * blockDim.x + threadIdx.x;
    if (idx >= HW) return;

    const __half2* uh = (const __half2*)u;
    const int h  = idx >> 1;
    const bool hi = (idx & 1) != 0;
    const size_t S = (size_t)DD * (HW / 2);

    float c[DD];
    float m = -INFINITY;
    #pragma unroll
    for (int d = 0; d < DD; d++) {
        __half2 a = uh[S + (size_t)d * (HW / 2) + h];                 // u1[d]
        float v = hi ? __high2float(a) : __low2float(a);
        if (d > 0) {
            __half2 b = uh[(size_t)(d - 1) * (HW / 2) + h];           // u0[d-1]
            v += hi ? __high2float(b) : __low2float(b);
        }
        if (d < DD - 1) {
            __half2 e = uh[2 * S + (size_t)(d + 1) * (HW / 2) + h];   // u2[d+1]
            v += hi ? __high2float(e) : __low2float(e);
        }
        c[d] = v;
        m = fmaxf(m, v);
    }
    float s = 0.f;
    #pragma unroll
    for (int d = 0; d < DD; d++) {
        c[d] = expf(c[d] - m);
        s += c[d];
    }
    const float inv = 1.f / s;

    float depth = 0.f, di_f = 0.f;
    #pragma unroll
    for (int d = 0; d < DD; d++) {
        float p = c[d] * inv;
        c[d] = p;
        out[2 * HW + (size_t)d * HW + idx] = p;
        depth += p * M[64 + d];       // uniform depth table
        di_f  += p * (float)d;
    }
    out[idx] = depth;

    int di = (int)di_f;
    di = min(max(di, 0), DD - 1);
    float cur = 0.f, nxt = 0.f;
    #pragma unroll
    for (int d = 0; d < DD; d++) {
        if (d == di)     cur = c[d];
        if (d == di + 1) nxt = c[d];
    }
    out[HW + idx] = cur + nxt;   // nxt stays 0 when di == DD-1
}

// ---------------------------------------------------------------------------
extern "C" void kernel_launch(void* const* d_in, const int* in_sizes, int n_in,
                              void* d_out, int out_size, void* d_ws, size_t ws_size,
                              hipStream_t stream) {
    const float* features = (const float*)d_in[0];
    const float* projs    = (const float*)d_in[1];
    const float* depthv   = (const float*)d_in[2];
    const float* regw     = (const float*)d_in[3];
    float* out = (float*)d_out;

    const size_t tf_elems  = (size_t)VV * HW * CC;       // 6.55M halves (13.1 MB)
    const size_t var_elems = (size_t)CC * DD * HW;       // 41.9M halves (83.9 MB)

    float*  M    = (float*)d_ws;                         // 96 floats used
    __half* tf   = (__half*)((char*)d_ws + 4096);
    __half* var  = tf + tf_elems;
    __half* u    = var + var_elems;                      // 3*DD*HW halves (15.7 MB)

    k_setup<<<1, 64, 0, stream>>>(projs, depthv, M);
    k_transpose<<<(VV * HW + 255) / 256, 256, 0, stream>>>(features, tf);

    k_var_t<<<HH * (DD / ND), WW, 0, stream>>>(tf, M, var);

    k_conv2d<<<64 * 32, WW, 0, stream>>>(var, regw, u);

    k_softmax<<<(HW + 255) / 256, 256, 0, stream>>>(u, M, out);
}